// Round 15
// baseline (494.406 us; speedup 1.0000x reference)
//
#include <hip/hip_runtime.h>
#include <math.h>
#include <stdint.h>

#define NDIM 128
#define B_GRAPHS 8192
#define IDX 16
#define EPG 32
#define NN (B_GRAPHS*IDX)      // 131072 nodes
#define NE (B_GRAPHS*EPG)      // 262144 edges

typedef short bf16x8 __attribute__((ext_vector_type(8)));
typedef float f32x4  __attribute__((ext_vector_type(4)));

__device__ inline unsigned short f2bf(float x) {
    union { float f; unsigned u; } v; v.f = x;
    unsigned r = v.u + 0x7fff + ((v.u >> 16) & 1);
    return (unsigned short)(r >> 16);
}
__device__ inline float bf2f(unsigned short b) {
    union { unsigned u; float f; } v; v.u = ((unsigned)b) << 16;
    return v.f;
}
__device__ inline float sigm(float x) { return 1.f/(1.f + __expf(-x)); }
__device__ inline float tanh_f(float x) {
    float ax = fabsf(x);
    float t  = __expf(-2.f*ax);
    float r  = (1.f - t)/(1.f + t);
    return copysignf(r, x);
}

#define GLOAD_LDS16(g, l) \
    __builtin_amdgcn_global_load_lds( \
        (const __attribute__((address_space(1))) unsigned int*)(g), \
        (__attribute__((address_space(3))) unsigned int*)(l), 16, 0, 0)

// ---------------------------------------------------------------------------
// composemm: heavy part of WB = Wih(384x256) @ [msgW|msgrW perm](256x512),
// LDS-tiled fp32 GEMM, 64x64 tiles, col-interleave applied at store.
// ---------------------------------------------------------------------------
__global__ __launch_bounds__(256) void composemm_kernel(
    const float* __restrict__ msg_W, const float* __restrict__ msgr_W,
    const float* __restrict__ Wih, unsigned short* __restrict__ WB)
{
    int bid = blockIdx.x;
    int l  = bid / 48; int rem = bid - l*48;
    int ct = rem >> 3, kt = rem & 7;
    const int t = threadIdx.x;
    __shared__ float Ws[64][33];
    __shared__ float Ms[32][65];
    const float* wih    = Wih   + (size_t)l*384*256;
    const float* msgWl  = msg_W + (size_t)l*256*256;
    const float* msgrWl = msgr_W+ (size_t)l*256*256;
    float acc[4][4] = {};
    const int tr  = (t >> 4) * 4;
    const int tcc = (t & 15) * 4;
    for (int q0 = 0; q0 < 256; q0 += 32) {
#pragma unroll
        for (int i = 0; i < 8; i++) {
            int u = i*256 + t; int r = u >> 5, q = u & 31;
            Ws[r][q] = wih[(size_t)(ct*64 + r)*256 + q0 + q];
        }
#pragma unroll
        for (int i = 0; i < 8; i++) {
            int u = i*256 + t; int q = u >> 6, c = u & 63;
            int kk = kt*64 + c;
            int piece = kk >> 7;
            const float* M = (piece & 1) ? msgrWl : msgWl;
            int sc = (kk & 127) + ((piece >> 1) << 7);
            Ms[q][c] = M[(size_t)(q0 + q)*256 + sc];
        }
        __syncthreads();
#pragma unroll 8
        for (int q = 0; q < 32; q++) {
#pragma unroll
            for (int i2 = 0; i2 < 4; i2++) {
                float wv = Ws[tr + i2][q];
#pragma unroll
                for (int j2 = 0; j2 < 4; j2++)
                    acc[i2][j2] = fmaf(wv, Ms[q][tcc + j2], acc[i2][j2]);
            }
        }
        __syncthreads();
    }
#pragma unroll
    for (int i2 = 0; i2 < 4; i2++) {
        int cold = ct*64 + tr + i2;
        int cc = cold & 127, t2 = cold >> 7;
        int colp = ((cc >> 4) << 6) + (t2 << 4) + (cc & 15);
#pragma unroll
        for (int j2 = 0; j2 < 4; j2++) {
            int k = kt*64 + tcc + j2;
            WB[(size_t)l*512*640 + (size_t)colp*640 + k] = f2bf(acc[i2][j2]);
        }
    }
}

// ---------------------------------------------------------------------------
// compose (cheap remainder): Whh copy / zero cols / bias dots.
// ---------------------------------------------------------------------------
__global__ __launch_bounds__(256) void compose_kernel(
    const float* __restrict__ msg_W, const float* __restrict__ msgr_W,
    const float* __restrict__ Wih,   const float* __restrict__ Whh,
    const float* __restrict__ msg_b, const float* __restrict__ msgr_b,
    unsigned short* __restrict__ WB, float* __restrict__ c34)
{
    int idx = blockIdx.x*256 + threadIdx.x;
    const int TWB = 2*512*640;
    if (idx < TWB) {
        int l = idx / (512*640); int rem = idx - l*(512*640);
        int cold = rem / 640; int k = rem - cold*640;
        float val;
        if (k < 512) {
            if (cold < 384) return;          // composemm handles
            val = 0.f;
        } else {
            int kk = k - 512;
            if (cold < 256)      val = Whh[l*384*128 + cold*128 + kk];
            else if (cold < 384) val = 0.f;
            else                 val = Whh[l*384*128 + (cold-128)*128 + kk];
        }
        int cc = cold & 127, t = cold >> 7;
        int colp = ((cc >> 4) << 6) + (t << 4) + (cc & 15);
        WB[l*512*640 + colp*640 + k] = f2bf(val);
    } else if (idx < TWB + 2*2*384) {
        int i2 = idx - TWB;
        int l = i2 / 768; int rem = i2 - l*768;
        int which = rem / 384; int r = rem - which*384;
        const float* wih = Wih + l*384*256 + r*256;
        const float* bb  = (which ? msgr_b : msg_b) + l*256;
        float acc = 0.f;
        for (int q = 0; q < 256; q++) acc = fmaf(wih[q], bb[q], acc);
        c34[l*768 + which*384 + r] = acc;
    }
}

// ---------------------------------------------------------------------------
// Init: per-graph edge decode + packed edges + A0 build (bf16, 16B stores).
// ---------------------------------------------------------------------------
__global__ __launch_bounds__(128) void init_kernel(
    const float* __restrict__ hin, const int* __restrict__ ei,
    unsigned short* __restrict__ A, unsigned char* __restrict__ pack)
{
    int g = blockIdx.x, t = threadIdx.x;
    __shared__ float hb[16][128];
    __shared__ float sin_[16][128];
    __shared__ float sout_[16][128];
    __shared__ int sl[32], dl[32];
    __shared__ int cin[16], cout[16];
    __shared__ int flag64;
    int base = g*IDX;
    for (int r = 0; r < 16; r++) hb[r][t] = hin[(size_t)(base+r)*128 + t];
    for (int r = 0; r < 16; r++) { sin_[r][t] = 0.f; sout_[r][t] = 0.f; }
    if (t < 16) { cin[t] = 0; cout[t] = 0; }
    if (t == 0) {
        int orv = 0;
        for (int i = 1; i < 64; i += 2) orv |= ei[i];
        flag64 = (orv == 0);
    }
    __syncthreads();
    if (t < 32) {
        int e = g*EPG + t;
        int sv, dv;
        if (flag64) { sv = ei[2*e]; dv = ei[2*(NE + e)]; }
        else        { sv = ei[e];   dv = ei[NE + e];     }
        sl[t] = sv - base; dl[t] = dv - base;
        atomicAdd(&cout[sl[t]], 1); atomicAdd(&cin[dl[t]], 1);
        pack[g*32 + t] = (unsigned char)((sl[t] & 15) | ((dl[t] & 15) << 4));
    }
    __syncthreads();
    for (int e = 0; e < 32; e++) {
        sin_[dl[e]][t]  += hb[sl[e]][t];
        sout_[sl[e]][t] += hb[dl[e]][t];
    }
    __syncthreads();   // write phase reads other threads' columns
    {
        size_t gbase = (size_t)base * 640;
#pragma unroll
        for (int i = 0; i < 10; i++) {
            int u = i*128 + t;             // 1280 bf16x8 units per graph
            int row = u / 80;
            int j   = u - row*80;
            int seg = j >> 4;
            int c0  = (j & 15) * 8;
            float vals[8];
            if (seg == 0) {
#pragma unroll
                for (int k2 = 0; k2 < 8; k2++) vals[k2] = sin_[row][c0+k2];
            } else if (seg == 1) {
#pragma unroll
                for (int k2 = 0; k2 < 8; k2++) vals[k2] = sout_[row][c0+k2];
            } else {
                float s = (seg == 2) ? (float)cin[row]
                        : (seg == 3) ? (float)cout[row] : 1.f;
#pragma unroll
                for (int k2 = 0; k2 < 8; k2++) vals[k2] = hb[row][c0+k2] * s;
            }
            bf16x8 w;
#pragma unroll
            for (int k2 = 0; k2 < 8; k2++) w[k2] = (short)f2bf(vals[k2]);
            *(bf16x8*)(A + gbase + (size_t)row*640 + seg*128 + c0) = w;
        }
    }
}

// ---------------------------------------------------------------------------
// Merged 2-layer GNN kernel. Block = 64 rows (4 graphs) x ALL 512 interleaved
// cols, 8 waves, acc[4][4] (64 AGPR), VGPR ~64 -> 2 blocks/CU. Both layers
// run in ONE dispatch (block-local dependency): layer 0 epilogue rewrites A
// (global), vmcnt(0)+barrier, layer 1 streams it back (L2-hot). Pool fused.
// ---------------------------------------------------------------------------
struct FSmem {
    unsigned short As[2][64*64];           // 16 KB (each buf = 2 K-steps)
    union {
        unsigned short Bs[2][384*32];      // 48 KB (K-loop)
        unsigned short hnewB[64*128];      // 16 KB (epilogue)
    } u;
    unsigned char csr[4][2][17];
    unsigned char adj[4][2][32];
    unsigned char offj[4][2][16];
    float gates[2][64];
};

#define MF(a,b,c) __builtin_amdgcn_mfma_f32_16x16x32_bf16((a),(b),(c),0,0,0)

#define CSTEP(BB, AB, E, J2) do {                                             \
    const unsigned short* Asb = sm.As[AB];                                    \
    const unsigned short* Bsb = sm.u.Bs[BB];                                  \
    bf16x8 bfv[3];                                                            \
    _Pragma("unroll")                                                         \
    for (int tt = 0; tt < 3; tt++) {                                          \
        int a0 = wid*48 + tt*16 + l15;                                        \
        bfv[tt] = *(const bf16x8*)(Bsb + a0*32 + (l4 ^ ((a0>>1)&3))*8);       \
    }                                                                         \
    bf16x8 afv[4];                                                            \
    _Pragma("unroll")                                                         \
    for (int mi = 0; mi < 4; mi++) {                                          \
        int row = mi*16 + l15;                                                \
        int slot = ((E)*4 + l4) ^ (row & 7);                                  \
        afv[mi] = *(const bf16x8*)(Asb + row*64 + slot*8);                    \
    }                                                                         \
    __builtin_amdgcn_s_setprio(1);                                            \
    _Pragma("unroll")                                                         \
    for (int mi = 0; mi < 4; mi++) {                                          \
        acc[mi][0]  = MF(afv[mi], bfv[0], acc[mi][0]);                        \
        acc[mi][1]  = MF(afv[mi], bfv[1], acc[mi][1]);                        \
        acc[mi][J2] = MF(afv[mi], bfv[2], acc[mi][J2]);                       \
    }                                                                         \
    __builtin_amdgcn_s_setprio(0);                                            \
} while (0)

#define WB0 asm volatile("s_waitcnt vmcnt(0)\n\ts_barrier" ::: "memory")
#define WB1 asm volatile("s_waitcnt vmcnt(1)\n\ts_barrier" ::: "memory")

__global__ __launch_bounds__(512, 4) void gnn_kernel(
    unsigned short* __restrict__ A,
    const unsigned short* __restrict__ WB,
    const unsigned char* __restrict__ pack,
    const float* __restrict__ c34,
    const float* __restrict__ bih, const float* __restrict__ bhh,
    const float* __restrict__ gmW,  const float* __restrict__ gmb,
    const float* __restrict__ gmiW, const float* __restrict__ gmib,
    float* __restrict__ hf, float* __restrict__ P1, float* __restrict__ P2,
    float* __restrict__ sg)
{
    __shared__ FSmem sm;
    const int n0  = blockIdx.x * 64;
    const int g0  = blockIdx.x * 4;
    const int tid = threadIdx.x;
    const int lane = tid & 63, wid = tid >> 6;   // wave owns 16 channels
    const int l15 = lane & 15, l4 = lane >> 4;

    const int arow = tid >> 3;
    unsigned short* Abase =
        A + (size_t)(n0 + arow)*640 + (size_t)(((tid & 7) ^ (arow & 7)) * 8);
    int boffv[3], baddv[3];
#pragma unroll
    for (int i = 0; i < 3; i++) {
        int u = i*512 + tid;
        int a = u >> 2, s = u & 3;
        int grp = a / 48, rem = a - grp*48;
        int tt = rem >> 4, clo = rem & 15;
        boffv[i] = (grp*64 + tt*16 + clo)*640 + (s ^ ((a >> 1) & 3))*8;
        baddv[i] = (tt == 2) ? 16*640 : 0;
    }

    // CSR build once (degrees layer-invariant); K-loop barriers publish it
    if (tid < 8) {
        int gl = tid >> 1, dir = tid & 1;
        const unsigned char* pk = pack + (size_t)(g0 + gl)*32;
        unsigned char* C = sm.csr[gl][dir];
        for (int d = 0; d < 17; d++) C[d] = 0;
        for (int e = 0; e < 32; e++) {
            int p = pk[e];
            int key = dir ? (p & 15) : (p >> 4);
            C[key + 1]++;
        }
        for (int d = 0; d < 16; d++) { C[d+1] += C[d]; sm.offj[gl][dir][d] = C[d]; }
        for (int e = 0; e < 32; e++) {
            int p = pk[e];
            int key = dir ? (p & 15) : (p >> 4);
            int val = dir ? (p >> 4) : (p & 15);
            sm.adj[gl][dir][sm.offj[gl][dir][key]++] = val;
        }
    }

    auto do_layer = [&](const unsigned short* WBl, const float* c34l,
                        const float* bihl, const float* bhhl, bool fin) {
        auto STAGE_A2 = [&](int p) {
            GLOAD_LDS16(Abase + p*64, sm.As[p & 1] + tid*8);
        };
        auto STAGE_B = [&](int kst) {
            unsigned short* dst = sm.u.Bs[kst & 1] + tid*8;
            const unsigned short* srcb = WBl + kst*32;
            if (kst < 16) {
#pragma unroll
                for (int i = 0; i < 3; i++)
                    GLOAD_LDS16(srcb + boffv[i], dst + i*4096);
            } else {
#pragma unroll
                for (int i = 0; i < 3; i++)
                    GLOAD_LDS16(srcb + boffv[i] + baddv[i], dst + i*4096);
            }
        };

        f32x4 acc[4][4] = {};

        STAGE_B(0); STAGE_A2(0);
        WB0;
        STAGE_B(1);  STAGE_A2(1); CSTEP(0, 0, 0, 2);     // ks 0
        WB1; STAGE_B(2);          CSTEP(1, 0, 1, 2);     // ks 1
        WB0; STAGE_B(3);  STAGE_A2(2); CSTEP(0, 1, 0, 2);// ks 2
        WB1; STAGE_B(4);          CSTEP(1, 1, 1, 2);     // ks 3
        WB0; STAGE_B(5);  STAGE_A2(3); CSTEP(0, 0, 0, 2);// ks 4
        WB1; STAGE_B(6);          CSTEP(1, 0, 1, 2);     // ks 5
        WB0; STAGE_B(7);  STAGE_A2(4); CSTEP(0, 1, 0, 2);// ks 6
        WB1; STAGE_B(8);          CSTEP(1, 1, 1, 2);     // ks 7
        WB0; STAGE_B(9);  STAGE_A2(5); CSTEP(0, 0, 0, 2);// ks 8
        WB1; STAGE_B(10);         CSTEP(1, 0, 1, 2);     // ks 9
        WB0; STAGE_B(11); STAGE_A2(6); CSTEP(0, 1, 0, 2);// ks 10
        WB1; STAGE_B(12);         CSTEP(1, 1, 1, 2);     // ks 11
        WB0; STAGE_B(13); STAGE_A2(7); CSTEP(0, 0, 0, 2);// ks 12
        WB1; STAGE_B(14);         CSTEP(1, 0, 1, 2);     // ks 13
        WB0; STAGE_B(15); STAGE_A2(8); CSTEP(0, 1, 0, 2);// ks 14
        WB1; STAGE_B(16);         CSTEP(1, 1, 1, 2);     // ks 15
        WB0; STAGE_B(17); STAGE_A2(9); CSTEP(0, 0, 0, 3);// ks 16
        WB1; STAGE_B(18);         CSTEP(1, 0, 1, 3);     // ks 17
        WB0; STAGE_B(19);         CSTEP(0, 1, 0, 3);     // ks 18
        WB0;                      CSTEP(1, 1, 1, 3);     // ks 19

        // ---- GRU: lane owns channel chn x 16 rows; hold from As chunks 8/9
        {
            const int chn = wid*16 + l15;
            const unsigned short* Ah = (chn < 64) ? sm.As[0] : sm.As[1];
            const int kl = chn & 63;
            float c3r = c34l[chn],     c3z = c34l[128+chn], c3n = c34l[256+chn];
            float c4r = c34l[384+chn], c4z = c34l[512+chn], c4n = c34l[640+chn];
            float br   = bihl[chn]     + bhhl[chn];
            float bz   = bihl[128+chn] + bhhl[128+chn];
            float bin_ = bihl[256+chn];
            float bhn_ = bhhl[256+chn];
#pragma unroll
            for (int mi = 0; mi < 4; mi++) {
#pragma unroll
                for (int q = 0; q < 4; q++) {
                    int row = mi*16 + l4*4 + q;
                    size_t v = (size_t)n0 + row;
                    int gl = row >> 4, d = row & 15;
                    float di  = (float)(sm.csr[gl][0][d+1] - sm.csr[gl][0][d]);
                    float dof = (float)(sm.csr[gl][1][d+1] - sm.csr[gl][1][d]);
                    float hold = bf2f(Ah[row*64 + (((kl>>3) ^ (row&7))<<3) + (kl&7)]);
                    float rr = sigm(acc[mi][0][q] + di*c3r + dof*c4r + br);
                    float zz = sigm(acc[mi][1][q] + di*c3z + dof*c4z + bz);
                    float nn = tanh_f(acc[mi][2][q] + di*c3n + dof*c4n + bin_
                                      + rr*(acc[mi][3][q] + bhn_));
                    float hv = nn + zz*(hold - nn);
                    *(unsigned short*)((char*)sm.u.hnewB
                        + row*256 + ((((chn>>3) ^ (row&7))<<4) + ((chn&7)<<1))) = f2bf(hv);
                    if (fin) hf[v*128 + chn] = hv;
                }
            }
        }
        __syncthreads();   // hnewB visible

        if (!fin) {
            // ---- vectorized gather + 16B A rewrite (block-local rows) ----
#pragma unroll
            for (int i = 0; i < 10; i++) {
                int u   = i*512 + tid;
                int seg = u >> 10;
                int row = (u >> 4) & 63;
                int c8  = u & 15;
                int gl = row >> 4, d = row & 15;
                float out8[8];
                if (seg < 2) {
#pragma unroll
                    for (int k = 0; k < 8; k++) out8[k] = 0.f;
                    int e0 = sm.csr[gl][seg][d], e1 = sm.csr[gl][seg][d+1];
                    int rb = gl*16;
                    for (int j = e0; j < e1; j++) {
                        int r2 = rb + sm.adj[gl][seg][j];
                        bf16x8 v8 = *(const bf16x8*)((const char*)sm.u.hnewB
                                     + r2*256 + ((c8 ^ (r2 & 7)) << 4));
#pragma unroll
                        for (int k = 0; k < 8; k++)
                            out8[k] += bf2f((unsigned short)v8[k]);
                    }
                } else {
                    bf16x8 v8 = *(const bf16x8*)((const char*)sm.u.hnewB
                                 + row*256 + ((c8 ^ (row & 7)) << 4));
                    float sc = 1.f;
                    if (seg == 2)
                        sc = (float)(sm.csr[gl][0][d+1] - sm.csr[gl][0][d]);
                    else if (seg == 3)
                        sc = (float)(sm.csr[gl][1][d+1] - sm.csr[gl][1][d]);
#pragma unroll
                    for (int k = 0; k < 8; k++)
                        out8[k] = bf2f((unsigned short)v8[k]) * sc;
                }
                bf16x8 w;
#pragma unroll
                for (int k = 0; k < 8; k++) w[k] = (short)f2bf(out8[k]);
                *(bf16x8*)(A + (size_t)(n0 + row)*640 + seg*128 + c8*8) = w;
            }
            // A stores must land (L2) + all hnewB readers done before layer-1
            // staging reads A / overwrites Bs[0].
            asm volatile("s_waitcnt vmcnt(0)" ::: "memory");
            __syncthreads();
        }
    };

    do_layer(WB,                    c34,       bih,       bhh,       false);
    do_layer(WB + (size_t)512*640,  c34 + 768, bih + 384, bhh + 384, true);

    // ---- fused gated pooling over the block's 4 graphs (hnewB = layer 1) --
    if (tid < 64) {
        int row = tid;
        float a1 = 0.f, a2 = 0.f;
        for (int s = 0; s < 16; s++) {
            bf16x8 hv8 = *(const bf16x8*)((const char*)sm.u.hnewB
                          + row*256 + ((s ^ (row & 7)) << 4));
#pragma unroll
            for (int j = 0; j < 8; j++) {
                float x = bf2f((unsigned short)hv8[j]);
                int c = s*8 + j;
                a1 = fmaf(gmW[c],  x, a1);
                a2 = fmaf(gmiW[c], x, a2);
            }
        }
        sm.gates[0][row] = sigm(a1 + gmb[0]);
        sm.gates[1][row] = sigm(a2 + gmib[0]);
    }
    __syncthreads();
    {
        int c = tid & 127, gq = tid >> 7;
        int rb = gq*16;
        float p1 = 0.f, p2 = 0.f;
        for (int r = 0; r < 16; r++) {
            int rr = rb + r;
            float x = bf2f(*(const unsigned short*)((const char*)sm.u.hnewB
                           + rr*256 + ((((c>>3) ^ (rr&7))<<4) + ((c&7)<<1))));
            p1 = fmaf(sm.gates[0][rr], x, p1);
            p2 = fmaf(sm.gates[1][rr], x, p2);
        }
        size_t g = g0 + gq;
        P1[g*128 + c] = p1;
        P2[g*128 + c] = p2;
    }
    if (tid < 8) {
        int gl = tid >> 1, w = tid & 1;
        float s = 0.f;
        for (int r = 0; r < 16; r++) s += sm.gates[w][gl*16 + r];
        sg[(size_t)(g0 + gl)*2 + w] = s;
    }
}

// ---------------------------------------------------------------------------
// Out projection: out[g][c] = fm_W[c].P[g] + fm_b[c]*sg[g].
// ---------------------------------------------------------------------------
__global__ __launch_bounds__(256) void outgemm_kernel(
    const float* __restrict__ P1, const float* __restrict__ P2,
    const float* __restrict__ sg,
    const float* __restrict__ fm_W,  const float* __restrict__ fm_b,
    const float* __restrict__ fmi_W, const float* __restrict__ fmi_b,
    float* __restrict__ out1, float* __restrict__ out2)
{
    const int g0 = blockIdx.x * 32;
    const int t  = threadIdx.x;
    __shared__ float Ws[128][33];
    __shared__ float Ps[32][33];
    const int tc = t & 15, tg = t >> 4;

    for (int pass = 0; pass < 2; pass++) {
        const float* P  = pass ? P2 : P1;
        const float* W  = pass ? fmi_W : fm_W;
        const float* bb = pass ? fmi_b : fm_b;
        float acc[2][8] = {};
        for (int kc = 0; kc < 128; kc += 32) {
#pragma unroll
            for (int i = 0; i < 16; i++) {
                int u = i*256 + t; int r = u >> 5, k = u & 31;
                Ws[r][k] = W[(size_t)r*128 + kc + k];
            }
#pragma unroll
            for (int i = 0; i < 4; i++) {
                int u = i*256 + t; int r = u >> 5, k = u & 31;
                Ps[r][k] = P[(size_t)(g0 + r)*128 + kc + k];
            }
            __syncthreads();
#pragma unroll 8
            for (int k = 0; k < 32; k++) {
                float p0 = Ps[tg*2][k], p1v = Ps[tg*2+1][k];
#pragma unroll
                for (int j = 0; j < 8; j++) {
                    float w = Ws[tc*8+j][k];
                    acc[0][j] = fmaf(p0,  w, acc[0][j]);
                    acc[1][j] = fmaf(p1v, w, acc[1][j]);
                }
            }
            __syncthreads();
        }
        float* outp = pass ? out2 : out1;
#pragma unroll
        for (int i = 0; i < 2; i++) {
            int g = g0 + tg*2 + i;
            float sgv = sg[g*2 + pass];
#pragma unroll
            for (int j = 0; j < 8; j++) {
                int cc = tc*8 + j;
                outp[(size_t)g*128 + cc] = acc[i][j] + bb[cc]*sgv;
            }
        }
    }
}

// ---------------------------------------------------------------------------
extern "C" void kernel_launch(void* const* d_in, const int* in_sizes, int n_in,
                              void* d_out, int out_size, void* d_ws, size_t ws_size,
                              hipStream_t stream)
{
    const float* h     = (const float*)d_in[0];
    const int*   ei    = (const int*)d_in[1];
    const float* msgW  = (const float*)d_in[2];
    const float* msgb  = (const float*)d_in[3];
    const float* msgrW = (const float*)d_in[4];
    const float* msgrb = (const float*)d_in[5];
    const float* Wih   = (const float*)d_in[6];
    const float* Whh   = (const float*)d_in[7];
    const float* bih   = (const float*)d_in[8];
    const float* bhh   = (const float*)d_in[9];
    const float* fmW   = (const float*)d_in[10];
    const float* fmb   = (const float*)d_in[11];
    const float* gmW   = (const float*)d_in[12];
    const float* gmb   = (const float*)d_in[13];
    const float* fmiW  = (const float*)d_in[14];
    const float* fmib  = (const float*)d_in[15];
    const float* gmiW  = (const float*)d_in[16];
    const float* gmib  = (const float*)d_in[17];

    char* w = (char*)d_ws;
    unsigned short* A    = (unsigned short*)w;  w += (size_t)NN*640*2;     // 167.8 MB
    unsigned short* WB   = (unsigned short*)w;  w += (size_t)2*512*640*2;  // 1.31 MB
    float* c34   = (float*)w;                   w += (size_t)2*768*4;
    unsigned char* pack = (unsigned char*)w;    w += (size_t)B_GRAPHS*32;
    float* P1    = (float*)w;                   w += (size_t)B_GRAPHS*128*4;
    float* P2    = (float*)w;                   w += (size_t)B_GRAPHS*128*4;
    float* sgb   = (float*)w;                   w += (size_t)B_GRAPHS*2*4;

    float* hf   = (float*)d_out;
    float* out1 = hf + (size_t)NN*128;
    float* out2 = out1 + (size_t)B_GRAPHS*128;

    composemm_kernel<<<96, 256, 0, stream>>>(msgW, msgrW, Wih, WB);
    int compose_items = 2*512*640 + 2*2*384;
    compose_kernel<<<(compose_items + 255)/256, 256, 0, stream>>>(
        msgW, msgrW, Wih, Whh, msgb, msgrb, WB, c34);

    init_kernel<<<B_GRAPHS, 128, 0, stream>>>(h, ei, A, pack);

    gnn_kernel<<<NN/64, 512, 0, stream>>>(
        A, WB, pack, c34, bih, bhh,
        gmW, gmb, gmiW, gmib, hf, P1, P2, sgb);

    outgemm_kernel<<<B_GRAPHS/32, 256, 0, stream>>>(
        P1, P2, sgb, fmW, fmb, fmiW, fmib, out1, out2);
}

// Round 16
// 392.011 us; speedup vs baseline: 1.2612x; 1.2612x over previous
//
#include <hip/hip_runtime.h>
#include <math.h>
#include <stdint.h>

#define NDIM 128
#define B_GRAPHS 8192
#define IDX 16
#define EPG 32
#define NN (B_GRAPHS*IDX)      // 131072 nodes
#define NE (B_GRAPHS*EPG)      // 262144 edges

typedef short bf16x8 __attribute__((ext_vector_type(8)));
typedef float f32x4  __attribute__((ext_vector_type(4)));

__device__ inline unsigned short f2bf(float x) {
    union { float f; unsigned u; } v; v.f = x;
    unsigned r = v.u + 0x7fff + ((v.u >> 16) & 1);
    return (unsigned short)(r >> 16);
}
__device__ inline float bf2f(unsigned short b) {
    union { unsigned u; float f; } v; v.u = ((unsigned)b) << 16;
    return v.f;
}
__device__ inline float sigm(float x) { return 1.f/(1.f + __expf(-x)); }
__device__ inline float tanh_f(float x) {
    float ax = fabsf(x);
    float t  = __expf(-2.f*ax);
    float r  = (1.f - t)/(1.f + t);
    return copysignf(r, x);
}

#define GLOAD_LDS16(g, l) \
    __builtin_amdgcn_global_load_lds( \
        (const __attribute__((address_space(1))) unsigned int*)(g), \
        (__attribute__((address_space(3))) unsigned int*)(l), 16, 0, 0)

// ---------------------------------------------------------------------------
// Compose bf16 weight matrix WB[l][col'][k] (512 cols x 640 K) and c34.
// K segments: [S_in(128)|S_out(128)|indeg*h(128)|outdeg*h(128)|h(128)]
// Column interleave: col' = (c>>4)*64 + type*16 + (c&15), type in {r,z,gin,ghn}
// ---------------------------------------------------------------------------
__global__ __launch_bounds__(256) void compose_kernel(
    const float* __restrict__ msg_W, const float* __restrict__ msgr_W,
    const float* __restrict__ Wih,   const float* __restrict__ Whh,
    const float* __restrict__ msg_b, const float* __restrict__ msgr_b,
    unsigned short* __restrict__ WB, float* __restrict__ c34)
{
    int idx = blockIdx.x*256 + threadIdx.x;
    const int TWB = 2*512*640;
    if (idx < TWB) {
        int l = idx / (512*640); int rem = idx - l*(512*640);
        int cold = rem / 640; int k = rem - cold*640;
        float val;
        if (k < 512) {
            if (cold < 384) {
                const float* wih = Wih + l*384*256 + cold*256;
                const float* M; int sc;
                if (k < 128)      { M = msg_W  + l*256*256; sc = k;       }
                else if (k < 256) { M = msgr_W + l*256*256; sc = k - 128; }
                else if (k < 384) { M = msg_W  + l*256*256; sc = k - 128; }
                else              { M = msgr_W + l*256*256; sc = k - 256; }
                float acc = 0.f;
                for (int q = 0; q < 256; q++) acc = fmaf(wih[q], M[q*256 + sc], acc);
                val = acc;
            } else val = 0.f;
        } else {
            int kk = k - 512;
            if (cold < 256)      val = Whh[l*384*128 + cold*128 + kk];
            else if (cold < 384) val = 0.f;
            else                 val = Whh[l*384*128 + (cold-128)*128 + kk];
        }
        int cc = cold & 127, t = cold >> 7;
        int colp = ((cc >> 4) << 6) + (t << 4) + (cc & 15);
        WB[l*512*640 + colp*640 + k] = f2bf(val);
    } else if (idx < TWB + 2*2*384) {
        int i2 = idx - TWB;
        int l = i2 / 768; int rem = i2 - l*768;
        int which = rem / 384; int r = rem - which*384;
        const float* wih = Wih + l*384*256 + r*256;
        const float* bb  = (which ? msgr_b : msg_b) + l*256;
        float acc = 0.f;
        for (int q = 0; q < 256; q++) acc = fmaf(wih[q], bb[q], acc);
        c34[l*768 + which*384 + r] = acc;
    }
}

// ---------------------------------------------------------------------------
// Init: per-graph edge decode + degree + packed edges + A0 build (bf16).
// ---------------------------------------------------------------------------
__global__ __launch_bounds__(128) void init_kernel(
    const float* __restrict__ hin, const int* __restrict__ ei,
    unsigned short* __restrict__ A, float* __restrict__ indeg,
    float* __restrict__ outdeg, unsigned char* __restrict__ pack)
{
    int g = blockIdx.x, t = threadIdx.x;
    __shared__ float hb[16][128];
    __shared__ float sin_[16][128];
    __shared__ float sout_[16][128];
    __shared__ int sl[32], dl[32];
    __shared__ int cin[16], cout[16];
    __shared__ int flag64;
    int base = g*IDX;
    for (int r = 0; r < 16; r++) hb[r][t] = hin[(size_t)(base+r)*128 + t];
    for (int r = 0; r < 16; r++) { sin_[r][t] = 0.f; sout_[r][t] = 0.f; }
    if (t < 16) { cin[t] = 0; cout[t] = 0; }
    if (t == 0) {
        int orv = 0;
        for (int i = 1; i < 64; i += 2) orv |= ei[i];
        flag64 = (orv == 0);
    }
    __syncthreads();
    if (t < 32) {
        int e = g*EPG + t;
        int sv, dv;
        if (flag64) { sv = ei[2*e]; dv = ei[2*(NE + e)]; }
        else        { sv = ei[e];   dv = ei[NE + e];     }
        sl[t] = sv - base; dl[t] = dv - base;
        atomicAdd(&cout[sl[t]], 1); atomicAdd(&cin[dl[t]], 1);
        pack[g*32 + t] = (unsigned char)((sl[t] & 15) | ((dl[t] & 15) << 4));
    }
    __syncthreads();
    for (int e = 0; e < 32; e++) {
        sin_[dl[e]][t]  += hb[sl[e]][t];
        sout_[sl[e]][t] += hb[dl[e]][t];
    }
    for (int r = 0; r < 16; r++) {
        size_t v = base + r;
        float di = (float)cin[r], dof = (float)cout[r];
        A[v*640 + t]        = f2bf(sin_[r][t]);
        A[v*640 + 128 + t]  = f2bf(sout_[r][t]);
        A[v*640 + 256 + t]  = f2bf(di  * hb[r][t]);
        A[v*640 + 384 + t]  = f2bf(dof * hb[r][t]);
        A[v*640 + 512 + t]  = f2bf(hb[r][t]);
    }
    if (t < 16) { indeg[base+t] = (float)cin[t]; outdeg[base+t] = (float)cout[t]; }
}

// ---------------------------------------------------------------------------
// Fused GEMM+GRU (+scatter / +pool). Block = 64 rows (4 graphs) x ALL 512
// interleaved cols, 8 waves, acc[4][4] (64 AGPR), VGPR 64 -> 2 blocks/CU,
// 4 waves/SIMD (occupancy 42%).
// B LDS swizzle f(a) = (a>>1)&3 -> 2-way bank access (free per m136),
// applied to BOTH the pre-swizzled global source and the ds_read slot
// (matched involution, rule #21); s_setprio(1) around the MFMA cluster (T5).
// Pipeline per step: vmcnt(N); s_barrier; STAGE(next); CSTEP(cur).
// ---------------------------------------------------------------------------
struct FSmem {
    unsigned short As[2][64*64];           // 16 KB (each buf = 2 K-steps)
    union {
        unsigned short Bs[2][384*32];      // 48 KB (K-loop)
        unsigned short hnewB[64*128];      // 16 KB (epilogue)
    } u;
    unsigned char csr[4][2][17];
    unsigned char adj[4][2][32];
    unsigned char offj[4][2][16];
    float gates[2][64];
};

#define MF(a,b,c) __builtin_amdgcn_mfma_f32_16x16x32_bf16((a),(b),(c),0,0,0)

#define CSTEP(BB, AB, E, J2) do {                                             \
    const unsigned short* Asb = sm.As[AB];                                    \
    const unsigned short* Bsb = sm.u.Bs[BB];                                  \
    bf16x8 bfv[3];                                                            \
    _Pragma("unroll")                                                         \
    for (int tt = 0; tt < 3; tt++) {                                          \
        int a0 = wid*48 + tt*16 + l15;                                        \
        bfv[tt] = *(const bf16x8*)(Bsb + a0*32 + (l4 ^ ((a0>>1)&3))*8);       \
    }                                                                         \
    bf16x8 afv[4];                                                            \
    _Pragma("unroll")                                                         \
    for (int mi = 0; mi < 4; mi++) {                                          \
        int row = mi*16 + l15;                                                \
        int slot = ((E)*4 + l4) ^ (row & 7);                                  \
        afv[mi] = *(const bf16x8*)(Asb + row*64 + slot*8);                    \
    }                                                                         \
    __builtin_amdgcn_s_setprio(1);                                            \
    _Pragma("unroll")                                                         \
    for (int mi = 0; mi < 4; mi++) {                                          \
        acc[mi][0]  = MF(afv[mi], bfv[0], acc[mi][0]);                        \
        acc[mi][1]  = MF(afv[mi], bfv[1], acc[mi][1]);                        \
        acc[mi][J2] = MF(afv[mi], bfv[2], acc[mi][J2]);                       \
    }                                                                         \
    __builtin_amdgcn_s_setprio(0);                                            \
} while (0)

#define WB0 asm volatile("s_waitcnt vmcnt(0)\n\ts_barrier" ::: "memory")
#define WB1 asm volatile("s_waitcnt vmcnt(1)\n\ts_barrier" ::: "memory")

template <bool FINAL>
__global__ __launch_bounds__(512, 4) void fused_kernel(
    unsigned short* __restrict__ A,
    const unsigned short* __restrict__ WBl,
    const unsigned char* __restrict__ pack,
    const float* __restrict__ c34l,
    const float* __restrict__ bihl, const float* __restrict__ bhhl,
    const float* __restrict__ gmW,  const float* __restrict__ gmb,
    const float* __restrict__ gmiW, const float* __restrict__ gmib,
    float* __restrict__ hf, float* __restrict__ P1, float* __restrict__ P2,
    float* __restrict__ sg)
{
    __shared__ FSmem sm;
    const int n0  = blockIdx.x * 64;
    const int g0  = blockIdx.x * 4;
    const int tid = threadIdx.x;
    const int lane = tid & 63, wid = tid >> 6;   // wave owns 16 channels
    const int l15 = lane & 15, l4 = lane >> 4;

    const int arow = tid >> 3;
    const unsigned short* Abase =
        A + (size_t)(n0 + arow)*640 + (size_t)(((tid & 7) ^ (arow & 7)) * 8);
    int boffv[3], baddv[3];
#pragma unroll
    for (int i = 0; i < 3; i++) {
        int u = i*512 + tid;
        int a = u >> 2, s = u & 3;
        int grp = a / 48, rem = a - grp*48;
        int tt = rem >> 4, clo = rem & 15;
        boffv[i] = (grp*64 + tt*16 + clo)*640 + (s ^ ((a >> 1) & 3))*8;
        baddv[i] = (tt == 2) ? 16*640 : 0;
    }

    auto STAGE_A2 = [&](int p) {
        GLOAD_LDS16(Abase + p*64, sm.As[p & 1] + tid*8);
    };
    auto STAGE_B = [&](int kst) {
        unsigned short* dst = sm.u.Bs[kst & 1] + tid*8;
        const unsigned short* srcb = WBl + kst*32;
        if (kst < 16) {
#pragma unroll
            for (int i = 0; i < 3; i++)
                GLOAD_LDS16(srcb + boffv[i], dst + i*4096);
        } else {
#pragma unroll
            for (int i = 0; i < 3; i++)
                GLOAD_LDS16(srcb + boffv[i] + baddv[i], dst + i*4096);
        }
    };

    // prologue stages; CSR build (both dispatches - GRU needs degs) overlaps
    STAGE_B(0); STAGE_A2(0);
    if (tid < 8) {
        int gl = tid >> 1, dir = tid & 1;
        const unsigned char* pk = pack + (size_t)(g0 + gl)*32;
        unsigned char* C = sm.csr[gl][dir];
        for (int d = 0; d < 17; d++) C[d] = 0;
        for (int e = 0; e < 32; e++) {
            int p = pk[e];
            int key = dir ? (p & 15) : (p >> 4);
            C[key + 1]++;
        }
        for (int d = 0; d < 16; d++) { C[d+1] += C[d]; sm.offj[gl][dir][d] = C[d]; }
        for (int e = 0; e < 32; e++) {
            int p = pk[e];
            int key = dir ? (p & 15) : (p >> 4);
            int val = dir ? (p >> 4) : (p & 15);
            sm.adj[gl][dir][sm.offj[gl][dir][key]++] = val;
        }
    }

    f32x4 acc[4][4] = {};

    WB0;
    STAGE_B(1);  STAGE_A2(1); CSTEP(0, 0, 0, 2);     // ks 0
    WB1; STAGE_B(2);          CSTEP(1, 0, 1, 2);     // ks 1
    WB0; STAGE_B(3);  STAGE_A2(2); CSTEP(0, 1, 0, 2);// ks 2
    WB1; STAGE_B(4);          CSTEP(1, 1, 1, 2);     // ks 3
    WB0; STAGE_B(5);  STAGE_A2(3); CSTEP(0, 0, 0, 2);// ks 4
    WB1; STAGE_B(6);          CSTEP(1, 0, 1, 2);     // ks 5
    WB0; STAGE_B(7);  STAGE_A2(4); CSTEP(0, 1, 0, 2);// ks 6
    WB1; STAGE_B(8);          CSTEP(1, 1, 1, 2);     // ks 7
    WB0; STAGE_B(9);  STAGE_A2(5); CSTEP(0, 0, 0, 2);// ks 8
    WB1; STAGE_B(10);         CSTEP(1, 0, 1, 2);     // ks 9
    WB0; STAGE_B(11); STAGE_A2(6); CSTEP(0, 1, 0, 2);// ks 10
    WB1; STAGE_B(12);         CSTEP(1, 1, 1, 2);     // ks 11
    WB0; STAGE_B(13); STAGE_A2(7); CSTEP(0, 0, 0, 2);// ks 12
    WB1; STAGE_B(14);         CSTEP(1, 0, 1, 2);     // ks 13
    WB0; STAGE_B(15); STAGE_A2(8); CSTEP(0, 1, 0, 2);// ks 14
    WB1; STAGE_B(16);         CSTEP(1, 1, 1, 2);     // ks 15
    WB0; STAGE_B(17); STAGE_A2(9); CSTEP(0, 0, 0, 3);// ks 16
    WB1; STAGE_B(18);         CSTEP(1, 0, 1, 3);     // ks 17
    WB0; STAGE_B(19);         CSTEP(0, 1, 0, 3);     // ks 18
    WB0;                      CSTEP(1, 1, 1, 3);     // ks 19

    // ---- GRU in registers: lane owns channel chn x 16 rows ----
    {
        const int chn = wid*16 + l15;
        float c3r = c34l[chn],     c3z = c34l[128+chn], c3n = c34l[256+chn];
        float c4r = c34l[384+chn], c4z = c34l[512+chn], c4n = c34l[640+chn];
        float br   = bihl[chn]     + bhhl[chn];
        float bz   = bihl[128+chn] + bhhl[128+chn];
        float bin_ = bihl[256+chn];
        float bhn_ = bhhl[256+chn];
#pragma unroll
        for (int mi = 0; mi < 4; mi++) {
#pragma unroll
            for (int q = 0; q < 4; q++) {
                int row = mi*16 + l4*4 + q;
                size_t v = (size_t)n0 + row;
                int gl = row >> 4, d = row & 15;
                float di  = (float)(sm.csr[gl][0][d+1] - sm.csr[gl][0][d]);
                float dof = (float)(sm.csr[gl][1][d+1] - sm.csr[gl][1][d]);
                float hold = bf2f(A[v*640 + 512 + chn]);
                float rr = sigm(acc[mi][0][q] + di*c3r + dof*c4r + br);
                float zz = sigm(acc[mi][1][q] + di*c3z + dof*c4z + bz);
                float nn = tanh_f(acc[mi][2][q] + di*c3n + dof*c4n + bin_
                                  + rr*(acc[mi][3][q] + bhn_));
                float hv = nn + zz*(hold - nn);
                *(unsigned short*)((char*)sm.u.hnewB
                    + row*256 + ((((chn>>3) ^ (row&7))<<4) + ((chn&7)<<1))) = f2bf(hv);
                if (FINAL) hf[v*128 + chn] = hv;
            }
        }
    }
    __syncthreads();   // hnewB visible

    if (!FINAL) {
        // ---- vectorized gather + 16B A rewrite (block-local rows) ----
#pragma unroll
        for (int i = 0; i < 10; i++) {
            int u   = i*512 + tid;
            int seg = u >> 10;
            int row = (u >> 4) & 63;
            int c8  = u & 15;
            int gl = row >> 4, d = row & 15;
            float out8[8];
            if (seg < 2) {
#pragma unroll
                for (int k = 0; k < 8; k++) out8[k] = 0.f;
                int e0 = sm.csr[gl][seg][d], e1 = sm.csr[gl][seg][d+1];
                int rb = gl*16;
                for (int j = e0; j < e1; j++) {
                    int r2 = rb + sm.adj[gl][seg][j];
                    bf16x8 v8 = *(const bf16x8*)((const char*)sm.u.hnewB
                                 + r2*256 + ((c8 ^ (r2 & 7)) << 4));
#pragma unroll
                    for (int k = 0; k < 8; k++)
                        out8[k] += bf2f((unsigned short)v8[k]);
                }
            } else {
                bf16x8 v8 = *(const bf16x8*)((const char*)sm.u.hnewB
                             + row*256 + ((c8 ^ (row & 7)) << 4));
                float sc = 1.f;
                if (seg == 2)
                    sc = (float)(sm.csr[gl][0][d+1] - sm.csr[gl][0][d]);
                else if (seg == 3)
                    sc = (float)(sm.csr[gl][1][d+1] - sm.csr[gl][1][d]);
#pragma unroll
                for (int k = 0; k < 8; k++)
                    out8[k] = bf2f((unsigned short)v8[k]) * sc;
            }
            bf16x8 w;
#pragma unroll
            for (int k = 0; k < 8; k++) w[k] = (short)f2bf(out8[k]);
            *(bf16x8*)(A + (size_t)(n0 + row)*640 + seg*128 + c8*8) = w;
        }
    } else {
        // ---- fused gated pooling over the block's 4 graphs ----
        if (tid < 64) {
            int row = tid;
            float a1 = 0.f, a2 = 0.f;
            for (int s = 0; s < 16; s++) {
                bf16x8 hv8 = *(const bf16x8*)((const char*)sm.u.hnewB
                              + row*256 + ((s ^ (row & 7)) << 4));
#pragma unroll
                for (int j = 0; j < 8; j++) {
                    float x = bf2f((unsigned short)hv8[j]);
                    int c = s*8 + j;
                    a1 = fmaf(gmW[c],  x, a1);
                    a2 = fmaf(gmiW[c], x, a2);
                }
            }
            sm.gates[0][row] = sigm(a1 + gmb[0]);
            sm.gates[1][row] = sigm(a2 + gmib[0]);
        }
        __syncthreads();
        int c = tid & 127, gq = tid >> 7;
        int rb = gq*16;
        float p1 = 0.f, p2 = 0.f;
        for (int r = 0; r < 16; r++) {
            int rr = rb + r;
            float x = bf2f(*(const unsigned short*)((const char*)sm.u.hnewB
                           + rr*256 + ((((c>>3) ^ (rr&7))<<4) + ((c&7)<<1))));
            p1 = fmaf(sm.gates[0][rr], x, p1);
            p2 = fmaf(sm.gates[1][rr], x, p2);
        }
        size_t g = g0 + gq;
        P1[g*128 + c] = p1;
        P2[g*128 + c] = p2;
        if (tid < 8) {
            int gl = tid >> 1, w = tid & 1;
            float s = 0.f;
            for (int r = 0; r < 16; r++) s += sm.gates[w][gl*16 + r];
            sg[(size_t)(g0 + gl)*2 + w] = s;
        }
    }
}

// ---------------------------------------------------------------------------
// Out projection: out[g][c] = fm_W[c].P[g] + fm_b[c]*sg[g].
// ---------------------------------------------------------------------------
__global__ __launch_bounds__(256) void outgemm_kernel(
    const float* __restrict__ P1, const float* __restrict__ P2,
    const float* __restrict__ sg,
    const float* __restrict__ fm_W,  const float* __restrict__ fm_b,
    const float* __restrict__ fmi_W, const float* __restrict__ fmi_b,
    float* __restrict__ out1, float* __restrict__ out2)
{
    const int g0 = blockIdx.x * 32;
    const int t  = threadIdx.x;
    __shared__ float Ws[128][33];
    __shared__ float Ps[32][33];
    const int tc = t & 15, tg = t >> 4;

    for (int pass = 0; pass < 2; pass++) {
        const float* P  = pass ? P2 : P1;
        const float* W  = pass ? fmi_W : fm_W;
        const float* bb = pass ? fmi_b : fm_b;
        float acc[2][8] = {};
        for (int kc = 0; kc < 128; kc += 32) {
#pragma unroll
            for (int i = 0; i < 16; i++) {
                int u = i*256 + t; int r = u >> 5, k = u & 31;
                Ws[r][k] = W[(size_t)r*128 + kc + k];
            }
#pragma unroll
            for (int i = 0; i < 4; i++) {
                int u = i*256 + t; int r = u >> 5, k = u & 31;
                Ps[r][k] = P[(size_t)(g0 + r)*128 + kc + k];
            }
            __syncthreads();
#pragma unroll 8
            for (int k = 0; k < 32; k++) {
                float p0 = Ps[tg*2][k], p1v = Ps[tg*2+1][k];
#pragma unroll
                for (int j = 0; j < 8; j++) {
                    float w = Ws[tc*8+j][k];
                    acc[0][j] = fmaf(p0,  w, acc[0][j]);
                    acc[1][j] = fmaf(p1v, w, acc[1][j]);
                }
            }
            __syncthreads();
        }
        float* outp = pass ? out2 : out1;
#pragma unroll
        for (int i = 0; i < 2; i++) {
            int g = g0 + tg*2 + i;
            float sgv = sg[g*2 + pass];
#pragma unroll
            for (int j = 0; j < 8; j++) {
                int cc = tc*8 + j;
                outp[(size_t)g*128 + cc] = acc[i][j] + bb[cc]*sgv;
            }
        }
    }
}

// ---------------------------------------------------------------------------
extern "C" void kernel_launch(void* const* d_in, const int* in_sizes, int n_in,
                              void* d_out, int out_size, void* d_ws, size_t ws_size,
                              hipStream_t stream)
{
    const float* h     = (const float*)d_in[0];
    const int*   ei    = (const int*)d_in[1];
    const float* msgW  = (const float*)d_in[2];
    const float* msgb  = (const float*)d_in[3];
    const float* msgrW = (const float*)d_in[4];
    const float* msgrb = (const float*)d_in[5];
    const float* Wih   = (const float*)d_in[6];
    const float* Whh   = (const float*)d_in[7];
    const float* bih   = (const float*)d_in[8];
    const float* bhh   = (const float*)d_in[9];
    const float* fmW   = (const float*)d_in[10];
    const float* fmb   = (const float*)d_in[11];
    const float* gmW   = (const float*)d_in[12];
    const float* gmb   = (const float*)d_in[13];
    const float* fmiW  = (const float*)d_in[14];
    const float* fmib  = (const float*)d_in[15];
    const float* gmiW  = (const float*)d_in[16];
    const float* gmib  = (const float*)d_in[17];

    char* w = (char*)d_ws;
    unsigned short* A    = (unsigned short*)w;  w += (size_t)NN*640*2;     // 167.8 MB
    unsigned short* WB   = (unsigned short*)w;  w += (size_t)2*512*640*2;  // 1.31 MB
    float* c34   = (float*)w;                   w += (size_t)2*768*4;
    float* indeg = (float*)w;                   w += (size_t)NN*4;
    float* outdeg= (float*)w;                   w += (size_t)NN*4;
    unsigned char* pack = (unsigned char*)w;    w += (size_t)B_GRAPHS*32;
    float* P1    = (float*)w;                   w += (size_t)B_GRAPHS*128*4;
    float* P2    = (float*)w;                   w += (size_t)B_GRAPHS*128*4;
    float* sgb   = (float*)w;                   w += (size_t)B_GRAPHS*2*4;

    float* hf   = (float*)d_out;
    float* out1 = hf + (size_t)NN*128;
    float* out2 = out1 + (size_t)B_GRAPHS*128;

    int compose_items = 2*512*640 + 2*2*384;
    compose_kernel<<<(compose_items + 255)/256, 256, 0, stream>>>(
        msgW, msgrW, Wih, Whh, msgb, msgrb, WB, c34);

    init_kernel<<<B_GRAPHS, 128, 0, stream>>>(h, ei, A, indeg, outdeg, pack);

    fused_kernel<false><<<NN/64, 512, 0, stream>>>(
        A, WB, pack, c34, bih, bhh,
        gmW, gmb, gmiW, gmib, nullptr, nullptr, nullptr, nullptr);
    fused_kernel<true><<<NN/64, 512, 0, stream>>>(
        A, WB + (size_t)512*640, pack,
        c34 + 768, bih + 384, bhh + 384,
        gmW, gmb, gmiW, gmib, hf, P1, P2, sgb);

    outgemm_kernel<<<B_GRAPHS/32, 256, 0, stream>>>(
        P1, P2, sgb, fmW, fmb, fmiW, fmib, out1, out2);
}

// Round 17
// 391.952 us; speedup vs baseline: 1.2614x; 1.0002x over previous
//
#include <hip/hip_runtime.h>
#include <math.h>
#include <stdint.h>

#define NDIM 128
#define B_GRAPHS 8192
#define IDX 16
#define EPG 32
#define NN (B_GRAPHS*IDX)      // 131072 nodes
#define NE (B_GRAPHS*EPG)      // 262144 edges

typedef short bf16x8 __attribute__((ext_vector_type(8)));
typedef float f32x4  __attribute__((ext_vector_type(4)));

__device__ inline unsigned short f2bf(float x) {
    union { float f; unsigned u; } v; v.f = x;
    unsigned r = v.u + 0x7fff + ((v.u >> 16) & 1);
    return (unsigned short)(r >> 16);
}
__device__ inline float bf2f(unsigned short b) {
    union { unsigned u; float f; } v; v.u = ((unsigned)b) << 16;
    return v.f;
}
__device__ inline float sigm(float x) { return 1.f/(1.f + __expf(-x)); }
__device__ inline float tanh_f(float x) {
    float ax = fabsf(x);
    float t  = __expf(-2.f*ax);
    float r  = (1.f - t)/(1.f + t);
    return copysignf(r, x);
}

#define GLOAD_LDS16(g, l) \
    __builtin_amdgcn_global_load_lds( \
        (const __attribute__((address_space(1))) unsigned int*)(g), \
        (__attribute__((address_space(3))) unsigned int*)(l), 16, 0, 0)

// ---------------------------------------------------------------------------
// Compose bf16 weight matrix WB[l][col'][k] (512 cols x 640 K) and c34.
// K segments: [S_in(128)|S_out(128)|indeg*h(128)|outdeg*h(128)|h(128)]
// Column interleave: col' = (c>>4)*64 + type*16 + (c&15), type in {r,z,gin,ghn}
// ---------------------------------------------------------------------------
__global__ __launch_bounds__(256) void compose_kernel(
    const float* __restrict__ msg_W, const float* __restrict__ msgr_W,
    const float* __restrict__ Wih,   const float* __restrict__ Whh,
    const float* __restrict__ msg_b, const float* __restrict__ msgr_b,
    unsigned short* __restrict__ WB, float* __restrict__ c34)
{
    int idx = blockIdx.x*256 + threadIdx.x;
    const int TWB = 2*512*640;
    if (idx < TWB) {
        int l = idx / (512*640); int rem = idx - l*(512*640);
        int cold = rem / 640; int k = rem - cold*640;
        float val;
        if (k < 512) {
            if (cold < 384) {
                const float* wih = Wih + l*384*256 + cold*256;
                const float* M; int sc;
                if (k < 128)      { M = msg_W  + l*256*256; sc = k;       }
                else if (k < 256) { M = msgr_W + l*256*256; sc = k - 128; }
                else if (k < 384) { M = msg_W  + l*256*256; sc = k - 128; }
                else              { M = msgr_W + l*256*256; sc = k - 256; }
                float acc = 0.f;
                for (int q = 0; q < 256; q++) acc = fmaf(wih[q], M[q*256 + sc], acc);
                val = acc;
            } else val = 0.f;
        } else {
            int kk = k - 512;
            if (cold < 256)      val = Whh[l*384*128 + cold*128 + kk];
            else if (cold < 384) val = 0.f;
            else                 val = Whh[l*384*128 + (cold-128)*128 + kk];
        }
        int cc = cold & 127, t = cold >> 7;
        int colp = ((cc >> 4) << 6) + (t << 4) + (cc & 15);
        WB[l*512*640 + colp*640 + k] = f2bf(val);
    } else if (idx < TWB + 2*2*384) {
        int i2 = idx - TWB;
        int l = i2 / 768; int rem = i2 - l*768;
        int which = rem / 384; int r = rem - which*384;
        const float* wih = Wih + l*384*256 + r*256;
        const float* bb  = (which ? msgr_b : msg_b) + l*256;
        float acc = 0.f;
        for (int q = 0; q < 256; q++) acc = fmaf(wih[q], bb[q], acc);
        c34[l*768 + which*384 + r] = acc;
    }
}

// ---------------------------------------------------------------------------
// Init: per-graph edge decode + packed edges + A0 build (bf16).
// ---------------------------------------------------------------------------
__global__ __launch_bounds__(128) void init_kernel(
    const float* __restrict__ hin, const int* __restrict__ ei,
    unsigned short* __restrict__ A, unsigned char* __restrict__ pack)
{
    int g = blockIdx.x, t = threadIdx.x;
    __shared__ float hb[16][128];
    __shared__ float sin_[16][128];
    __shared__ float sout_[16][128];
    __shared__ int sl[32], dl[32];
    __shared__ int cin[16], cout[16];
    __shared__ int flag64;
    int base = g*IDX;
    for (int r = 0; r < 16; r++) hb[r][t] = hin[(size_t)(base+r)*128 + t];
    for (int r = 0; r < 16; r++) { sin_[r][t] = 0.f; sout_[r][t] = 0.f; }
    if (t < 16) { cin[t] = 0; cout[t] = 0; }
    if (t == 0) {
        int orv = 0;
        for (int i = 1; i < 64; i += 2) orv |= ei[i];
        flag64 = (orv == 0);
    }
    __syncthreads();
    if (t < 32) {
        int e = g*EPG + t;
        int sv, dv;
        if (flag64) { sv = ei[2*e]; dv = ei[2*(NE + e)]; }
        else        { sv = ei[e];   dv = ei[NE + e];     }
        sl[t] = sv - base; dl[t] = dv - base;
        atomicAdd(&cout[sl[t]], 1); atomicAdd(&cin[dl[t]], 1);
        pack[g*32 + t] = (unsigned char)((sl[t] & 15) | ((dl[t] & 15) << 4));
    }
    __syncthreads();
    for (int e = 0; e < 32; e++) {
        sin_[dl[e]][t]  += hb[sl[e]][t];
        sout_[sl[e]][t] += hb[dl[e]][t];
    }
    for (int r = 0; r < 16; r++) {
        size_t v = base + r;
        float di = (float)cin[r], dof = (float)cout[r];
        A[v*640 + t]        = f2bf(sin_[r][t]);
        A[v*640 + 128 + t]  = f2bf(sout_[r][t]);
        A[v*640 + 256 + t]  = f2bf(di  * hb[r][t]);
        A[v*640 + 384 + t]  = f2bf(dof * hb[r][t]);
        A[v*640 + 512 + t]  = f2bf(hb[r][t]);
    }
}

// ---------------------------------------------------------------------------
// Fused GEMM+GRU (+scatter / +pool). Block = 64 rows (4 graphs) x ALL 512
// interleaved cols, 8 waves, acc[4][4] (64 AGPR), VGPR 64 -> 2 blocks/CU,
// 4 waves/SIMD (occupancy 42%).
// B LDS swizzle f(a) = (a>>1)&3 -> 2-way bank access (free per m136),
// applied to BOTH the pre-swizzled global source and the ds_read slot
// (matched involution, rule #21); s_setprio(1) around the MFMA cluster (T5).
// Pipeline per step: vmcnt(N); s_barrier; STAGE(next); CSTEP(cur).
// Structural note (rounds 7-15 ablations): B prefetch distance is pinned at
// 1 step by the 2x24KB double buffer (3-ring = 88KB > 80KB 2-block budget);
// deeper acc tiles (128 AGPR) cap occupancy at 2 waves/SIMD - both measured
// worse. This config is the empirical optimum of that trade surface.
// ---------------------------------------------------------------------------
struct FSmem {
    unsigned short As[2][64*64];           // 16 KB (each buf = 2 K-steps)
    union {
        unsigned short Bs[2][384*32];      // 48 KB (K-loop)
        unsigned short hnewB[64*128];      // 16 KB (epilogue)
    } u;
    unsigned char csr[4][2][17];
    unsigned char adj[4][2][32];
    unsigned char offj[4][2][16];
    float gates[2][64];
};

#define MF(a,b,c) __builtin_amdgcn_mfma_f32_16x16x32_bf16((a),(b),(c),0,0,0)

#define CSTEP(BB, AB, E, J2) do {                                             \
    const unsigned short* Asb = sm.As[AB];                                    \
    const unsigned short* Bsb = sm.u.Bs[BB];                                  \
    bf16x8 bfv[3];                                                            \
    _Pragma("unroll")                                                         \
    for (int tt = 0; tt < 3; tt++) {                                          \
        int a0 = wid*48 + tt*16 + l15;                                        \
        bfv[tt] = *(const bf16x8*)(Bsb + a0*32 + (l4 ^ ((a0>>1)&3))*8);       \
    }                                                                         \
    bf16x8 afv[4];                                                            \
    _Pragma("unroll")                                                         \
    for (int mi = 0; mi < 4; mi++) {                                          \
        int row = mi*16 + l15;                                                \
        int slot = ((E)*4 + l4) ^ (row & 7);                                  \
        afv[mi] = *(const bf16x8*)(Asb + row*64 + slot*8);                    \
    }                                                                         \
    __builtin_amdgcn_s_setprio(1);                                            \
    _Pragma("unroll")                                                         \
    for (int mi = 0; mi < 4; mi++) {                                          \
        acc[mi][0]  = MF(afv[mi], bfv[0], acc[mi][0]);                        \
        acc[mi][1]  = MF(afv[mi], bfv[1], acc[mi][1]);                        \
        acc[mi][J2] = MF(afv[mi], bfv[2], acc[mi][J2]);                       \
    }                                                                         \
    __builtin_amdgcn_s_setprio(0);                                            \
} while (0)

#define WB0 asm volatile("s_waitcnt vmcnt(0)\n\ts_barrier" ::: "memory")
#define WB1 asm volatile("s_waitcnt vmcnt(1)\n\ts_barrier" ::: "memory")

template <bool FINAL>
__global__ __launch_bounds__(512, 4) void fused_kernel(
    unsigned short* __restrict__ A,
    const unsigned short* __restrict__ WBl,
    const unsigned char* __restrict__ pack,
    const float* __restrict__ c34l,
    const float* __restrict__ bihl, const float* __restrict__ bhhl,
    const float* __restrict__ gmW,  const float* __restrict__ gmb,
    const float* __restrict__ gmiW, const float* __restrict__ gmib,
    float* __restrict__ hf, float* __restrict__ P1, float* __restrict__ P2,
    float* __restrict__ sg)
{
    __shared__ FSmem sm;
    const int n0  = blockIdx.x * 64;
    const int g0  = blockIdx.x * 4;
    const int tid = threadIdx.x;
    const int lane = tid & 63, wid = tid >> 6;   // wave owns 16 channels
    const int l15 = lane & 15, l4 = lane >> 4;

    const int arow = tid >> 3;
    const unsigned short* Abase =
        A + (size_t)(n0 + arow)*640 + (size_t)(((tid & 7) ^ (arow & 7)) * 8);
    int boffv[3], baddv[3];
#pragma unroll
    for (int i = 0; i < 3; i++) {
        int u = i*512 + tid;
        int a = u >> 2, s = u & 3;
        int grp = a / 48, rem = a - grp*48;
        int tt = rem >> 4, clo = rem & 15;
        boffv[i] = (grp*64 + tt*16 + clo)*640 + (s ^ ((a >> 1) & 3))*8;
        baddv[i] = (tt == 2) ? 16*640 : 0;
    }

    auto STAGE_A2 = [&](int p) {
        GLOAD_LDS16(Abase + p*64, sm.As[p & 1] + tid*8);
    };
    auto STAGE_B = [&](int kst) {
        unsigned short* dst = sm.u.Bs[kst & 1] + tid*8;
        const unsigned short* srcb = WBl + kst*32;
        if (kst < 16) {
#pragma unroll
            for (int i = 0; i < 3; i++)
                GLOAD_LDS16(srcb + boffv[i], dst + i*4096);
        } else {
#pragma unroll
            for (int i = 0; i < 3; i++)
                GLOAD_LDS16(srcb + boffv[i] + baddv[i], dst + i*4096);
        }
    };

    // prologue stages; CSR build (both dispatches - GRU needs degs) overlaps
    STAGE_B(0); STAGE_A2(0);
    if (tid < 8) {
        int gl = tid >> 1, dir = tid & 1;
        const unsigned char* pk = pack + (size_t)(g0 + gl)*32;
        unsigned char* C = sm.csr[gl][dir];
        for (int d = 0; d < 17; d++) C[d] = 0;
        for (int e = 0; e < 32; e++) {
            int p = pk[e];
            int key = dir ? (p & 15) : (p >> 4);
            C[key + 1]++;
        }
        for (int d = 0; d < 16; d++) { C[d+1] += C[d]; sm.offj[gl][dir][d] = C[d]; }
        for (int e = 0; e < 32; e++) {
            int p = pk[e];
            int key = dir ? (p & 15) : (p >> 4);
            int val = dir ? (p >> 4) : (p & 15);
            sm.adj[gl][dir][sm.offj[gl][dir][key]++] = val;
        }
    }

    f32x4 acc[4][4] = {};

    WB0;
    STAGE_B(1);  STAGE_A2(1); CSTEP(0, 0, 0, 2);     // ks 0
    WB1; STAGE_B(2);          CSTEP(1, 0, 1, 2);     // ks 1
    WB0; STAGE_B(3);  STAGE_A2(2); CSTEP(0, 1, 0, 2);// ks 2
    WB1; STAGE_B(4);          CSTEP(1, 1, 1, 2);     // ks 3
    WB0; STAGE_B(5);  STAGE_A2(3); CSTEP(0, 0, 0, 2);// ks 4
    WB1; STAGE_B(6);          CSTEP(1, 0, 1, 2);     // ks 5
    WB0; STAGE_B(7);  STAGE_A2(4); CSTEP(0, 1, 0, 2);// ks 6
    WB1; STAGE_B(8);          CSTEP(1, 1, 1, 2);     // ks 7
    WB0; STAGE_B(9);  STAGE_A2(5); CSTEP(0, 0, 0, 2);// ks 8
    WB1; STAGE_B(10);         CSTEP(1, 0, 1, 2);     // ks 9
    WB0; STAGE_B(11); STAGE_A2(6); CSTEP(0, 1, 0, 2);// ks 10
    WB1; STAGE_B(12);         CSTEP(1, 1, 1, 2);     // ks 11
    WB0; STAGE_B(13); STAGE_A2(7); CSTEP(0, 0, 0, 2);// ks 12
    WB1; STAGE_B(14);         CSTEP(1, 0, 1, 2);     // ks 13
    WB0; STAGE_B(15); STAGE_A2(8); CSTEP(0, 1, 0, 2);// ks 14
    WB1; STAGE_B(16);         CSTEP(1, 1, 1, 2);     // ks 15
    WB0; STAGE_B(17); STAGE_A2(9); CSTEP(0, 0, 0, 3);// ks 16
    WB1; STAGE_B(18);         CSTEP(1, 0, 1, 3);     // ks 17
    WB0; STAGE_B(19);         CSTEP(0, 1, 0, 3);     // ks 18
    WB0;                      CSTEP(1, 1, 1, 3);     // ks 19

    // ---- GRU in registers: lane owns channel chn x 16 rows ----
    {
        const int chn = wid*16 + l15;
        float c3r = c34l[chn],     c3z = c34l[128+chn], c3n = c34l[256+chn];
        float c4r = c34l[384+chn], c4z = c34l[512+chn], c4n = c34l[640+chn];
        float br   = bihl[chn]     + bhhl[chn];
        float bz   = bihl[128+chn] + bhhl[128+chn];
        float bin_ = bihl[256+chn];
        float bhn_ = bhhl[256+chn];
#pragma unroll
        for (int mi = 0; mi < 4; mi++) {
#pragma unroll
            for (int q = 0; q < 4; q++) {
                int row = mi*16 + l4*4 + q;
                size_t v = (size_t)n0 + row;
                int gl = row >> 4, d = row & 15;
                float di  = (float)(sm.csr[gl][0][d+1] - sm.csr[gl][0][d]);
                float dof = (float)(sm.csr[gl][1][d+1] - sm.csr[gl][1][d]);
                float hold = bf2f(A[v*640 + 512 + chn]);
                float rr = sigm(acc[mi][0][q] + di*c3r + dof*c4r + br);
                float zz = sigm(acc[mi][1][q] + di*c3z + dof*c4z + bz);
                float nn = tanh_f(acc[mi][2][q] + di*c3n + dof*c4n + bin_
                                  + rr*(acc[mi][3][q] + bhn_));
                float hv = nn + zz*(hold - nn);
                *(unsigned short*)((char*)sm.u.hnewB
                    + row*256 + ((((chn>>3) ^ (row&7))<<4) + ((chn&7)<<1))) = f2bf(hv);
                if (FINAL) hf[v*128 + chn] = hv;
            }
        }
    }
    __syncthreads();   // hnewB visible

    if (!FINAL) {
        // ---- vectorized gather + 16B A rewrite (block-local rows) ----
#pragma unroll
        for (int i = 0; i < 10; i++) {
            int u   = i*512 + tid;
            int seg = u >> 10;
            int row = (u >> 4) & 63;
            int c8  = u & 15;
            int gl = row >> 4, d = row & 15;
            float out8[8];
            if (seg < 2) {
#pragma unroll
                for (int k = 0; k < 8; k++) out8[k] = 0.f;
                int e0 = sm.csr[gl][seg][d], e1 = sm.csr[gl][seg][d+1];
                int rb = gl*16;
                for (int j = e0; j < e1; j++) {
                    int r2 = rb + sm.adj[gl][seg][j];
                    bf16x8 v8 = *(const bf16x8*)((const char*)sm.u.hnewB
                                 + r2*256 + ((c8 ^ (r2 & 7)) << 4));
#pragma unroll
                    for (int k = 0; k < 8; k++)
                        out8[k] += bf2f((unsigned short)v8[k]);
                }
            } else {
                bf16x8 v8 = *(const bf16x8*)((const char*)sm.u.hnewB
                             + row*256 + ((c8 ^ (row & 7)) << 4));
                float sc = 1.f;
                if (seg == 2)
                    sc = (float)(sm.csr[gl][0][d+1] - sm.csr[gl][0][d]);
                else if (seg == 3)
                    sc = (float)(sm.csr[gl][1][d+1] - sm.csr[gl][1][d]);
#pragma unroll
                for (int k = 0; k < 8; k++)
                    out8[k] = bf2f((unsigned short)v8[k]) * sc;
            }
            bf16x8 w;
#pragma unroll
            for (int k = 0; k < 8; k++) w[k] = (short)f2bf(out8[k]);
            *(bf16x8*)(A + (size_t)(n0 + row)*640 + seg*128 + c8*8) = w;
        }
    } else {
        // ---- fused gated pooling over the block's 4 graphs ----
        if (tid < 64) {
            int row = tid;
            float a1 = 0.f, a2 = 0.f;
            for (int s = 0; s < 16; s++) {
                bf16x8 hv8 = *(const bf16x8*)((const char*)sm.u.hnewB
                              + row*256 + ((s ^ (row & 7)) << 4));
#pragma unroll
                for (int j = 0; j < 8; j++) {
                    float x = bf2f((unsigned short)hv8[j]);
                    int c = s*8 + j;
                    a1 = fmaf(gmW[c],  x, a1);
                    a2 = fmaf(gmiW[c], x, a2);
                }
            }
            sm.gates[0][row] = sigm(a1 + gmb[0]);
            sm.gates[1][row] = sigm(a2 + gmib[0]);
        }
        __syncthreads();
        int c = tid & 127, gq = tid >> 7;
        int rb = gq*16;
        float p1 = 0.f, p2 = 0.f;
        for (int r = 0; r < 16; r++) {
            int rr = rb + r;
            float x = bf2f(*(const unsigned short*)((const char*)sm.u.hnewB
                           + rr*256 + ((((c>>3) ^ (rr&7))<<4) + ((c&7)<<1))));
            p1 = fmaf(sm.gates[0][rr], x, p1);
            p2 = fmaf(sm.gates[1][rr], x, p2);
        }
        size_t g = g0 + gq;
        P1[g*128 + c] = p1;
        P2[g*128 + c] = p2;
        if (tid < 8) {
            int gl = tid >> 1, w = tid & 1;
            float s = 0.f;
            for (int r = 0; r < 16; r++) s += sm.gates[w][gl*16 + r];
            sg[(size_t)(g0 + gl)*2 + w] = s;
        }
    }
}

// ---------------------------------------------------------------------------
// Out projection: out[g][c] = fm_W[c].P[g] + fm_b[c]*sg[g].
// ---------------------------------------------------------------------------
__global__ __launch_bounds__(256) void outgemm_kernel(
    const float* __restrict__ P1, const float* __restrict__ P2,
    const float* __restrict__ sg,
    const float* __restrict__ fm_W,  const float* __restrict__ fm_b,
    const float* __restrict__ fmi_W, const float* __restrict__ fmi_b,
    float* __restrict__ out1, float* __restrict__ out2)
{
    const int g0 = blockIdx.x * 32;
    const int t  = threadIdx.x;
    __shared__ float Ws[128][33];
    __shared__ float Ps[32][33];
    const int tc = t & 15, tg = t >> 4;

    for (int pass = 0; pass < 2; pass++) {
        const float* P  = pass ? P2 : P1;
        const float* W  = pass ? fmi_W : fm_W;
        const float* bb = pass ? fmi_b : fm_b;
        float acc[2][8] = {};
        for (int kc = 0; kc < 128; kc += 32) {
#pragma unroll
            for (int i = 0; i < 16; i++) {
                int u = i*256 + t; int r = u >> 5, k = u & 31;
                Ws[r][k] = W[(size_t)r*128 + kc + k];
            }
#pragma unroll
            for (int i = 0; i < 4; i++) {
                int u = i*256 + t; int r = u >> 5, k = u & 31;
                Ps[r][k] = P[(size_t)(g0 + r)*128 + kc + k];
            }
            __syncthreads();
#pragma unroll 8
            for (int k = 0; k < 32; k++) {
                float p0 = Ps[tg*2][k], p1v = Ps[tg*2+1][k];
#pragma unroll
                for (int j = 0; j < 8; j++) {
                    float w = Ws[tc*8+j][k];
                    acc[0][j] = fmaf(p0,  w, acc[0][j]);
                    acc[1][j] = fmaf(p1v, w, acc[1][j]);
                }
            }
            __syncthreads();
        }
        float* outp = pass ? out2 : out1;
#pragma unroll
        for (int i = 0; i < 2; i++) {
            int g = g0 + tg*2 + i;
            float sgv = sg[g*2 + pass];
#pragma unroll
            for (int j = 0; j < 8; j++) {
                int cc = tc*8 + j;
                outp[(size_t)g*128 + cc] = acc[i][j] + bb[cc]*sgv;
            }
        }
    }
}

// ---------------------------------------------------------------------------
extern "C" void kernel_launch(void* const* d_in, const int* in_sizes, int n_in,
                              void* d_out, int out_size, void* d_ws, size_t ws_size,
                              hipStream_t stream)
{
    const float* h     = (const float*)d_in[0];
    const int*   ei    = (const int*)d_in[1];
    const float* msgW  = (const float*)d_in[2];
    const float* msgb  = (const float*)d_in[3];
    const float* msgrW = (const float*)d_in[4];
    const float* msgrb = (const float*)d_in[5];
    const float* Wih   = (const float*)d_in[6];
    const float* Whh   = (const float*)d_in[7];
    const float* bih   = (const float*)d_in[8];
    const float* bhh   = (const float*)d_in[9];
    const float* fmW   = (const float*)d_in[10];
    const float* fmb   = (const float*)d_in[11];
    const float* gmW   = (const float*)d_in[12];
    const float* gmb   = (const float*)d_in[13];
    const float* fmiW  = (const float*)d_in[14];
    const float* fmib  = (const float*)d_in[15];
    const float* gmiW  = (const float*)d_in[16];
    const float* gmib  = (const float*)d_in[17];

    char* w = (char*)d_ws;
    unsigned short* A    = (unsigned short*)w;  w += (size_t)NN*640*2;     // 167.8 MB
    unsigned short* WB   = (unsigned short*)w;  w += (size_t)2*512*640*2;  // 1.31 MB
    float* c34   = (float*)w;                   w += (size_t)2*768*4;
    unsigned char* pack = (unsigned char*)w;    w += (size_t)B_GRAPHS*32;
    float* P1    = (float*)w;                   w += (size_t)B_GRAPHS*128*4;
    float* P2    = (float*)w;                   w += (size_t)B_GRAPHS*128*4;
    float* sgb   = (float*)w;                   w += (size_t)B_GRAPHS*2*4;

    float* hf   = (float*)d_out;
    float* out1 = hf + (size_t)NN*128;
    float* out2 = out1 + (size_t)B_GRAPHS*128;

    int compose_items = 2*512*640 + 2*2*384;
    compose_kernel<<<(compose_items + 255)/256, 256, 0, stream>>>(
        msgW, msgrW, Wih, Whh, msgb, msgrb, WB, c34);

    init_kernel<<<B_GRAPHS, 128, 0, stream>>>(h, ei, A, pack);

    fused_kernel<false><<<NN/64, 512, 0, stream>>>(
        A, WB, pack, c34, bih, bhh,
        gmW, gmb, gmiW, gmib, nullptr, nullptr, nullptr, nullptr);
    fused_kernel<true><<<NN/64, 512, 0, stream>>>(
        A, WB + (size_t)512*640, pack,
        c34 + 768, bih + 384, bhh + 384,
        gmW, gmb, gmiW, gmib, hf, P1, P2, sgb);

    outgemm_kernel<<<B_GRAPHS/32, 256, 0, stream>>>(
        P1, P2, sgb, fmW, fmb, fmiW, fmib, out1, out2);
}